// Round 1
// baseline (721.408 us; speedup 1.0000x reference)
//
#include <hip/hip_runtime.h>
#include <hip/hip_bf16.h>
#include <math.h>

typedef __bf16 bf16x8 __attribute__((ext_vector_type(8)));
typedef float floatx4 __attribute__((ext_vector_type(4)));
typedef unsigned short ushort8 __attribute__((ext_vector_type(8)));
typedef unsigned short ushort4v __attribute__((ext_vector_type(4)));

__device__ __forceinline__ unsigned short f2bs(float f){
  union { float f; unsigned u; } v; v.f = f;
  unsigned r = v.u + 0x7fffu + ((v.u >> 16) & 1u);
  return (unsigned short)(r >> 16);
}

__device__ __forceinline__ void gl_lds16(const void* g, void* l){
  __builtin_amdgcn_global_load_lds(
      (const __attribute__((address_space(1))) void*)g,
      (__attribute__((address_space(3))) void*)l,
      16, 0, 0);
}

// ---------------- elementwise convert x -> bf16 ----------------
__global__ __launch_bounds__(256) void cvt_x(const float* __restrict__ x,
                                             unsigned short* __restrict__ o){
  const int i = (blockIdx.x*256 + threadIdx.x)*4;
  const float4 v = *(const float4*)(x + i);
  ushort4v u = { f2bs(v.x), f2bs(v.y), f2bs(v.z), f2bs(v.w) };
  *(ushort4v*)(o + i) = u;
}

// ---------------- generic fp32 [R][C] -> bf16 [C][R] transpose ----------------
__global__ __launch_bounds__(256) void transpose_pack(const float* __restrict__ src,
                                                      unsigned short* __restrict__ dst,
                                                      int R, int C){
  __shared__ float tile[32][65];
  const int r0 = blockIdx.y*32, c0 = blockIdx.x*64;
  const int t = threadIdx.x;
  {
    const int r = t >> 3, cc = (t & 7)*8;
    const float* p = src + (size_t)(r0+r)*C + c0 + cc;
    const float4 v0 = *(const float4*)p;
    const float4 v1 = *(const float4*)(p+4);
    tile[r][cc+0]=v0.x; tile[r][cc+1]=v0.y; tile[r][cc+2]=v0.z; tile[r][cc+3]=v0.w;
    tile[r][cc+4]=v1.x; tile[r][cc+5]=v1.y; tile[r][cc+6]=v1.z; tile[r][cc+7]=v1.w;
  }
  __syncthreads();
  const int f = t >> 2, rr = (t & 3)*8;
  ushort8 u;
  #pragma unroll
  for (int j=0;j<8;j++) u[j] = f2bs(tile[rr+j][f]);
  *(ushort8*)(dst + (size_t)(c0+f)*R + r0 + rr) = u;
}

// ---------------- pack wq/wk/wv [H,D,HD] -> Wqkv_t [3072][1024] bf16 + bias ----------------
__global__ __launch_bounds__(256) void pack_qkv(const float* __restrict__ wq,
                                                const float* __restrict__ wk,
                                                const float* __restrict__ wv,
                                                const float* __restrict__ bq,
                                                const float* __restrict__ bk,
                                                const float* __restrict__ bv,
                                                unsigned short* __restrict__ Wt,
                                                float* __restrict__ Bc){
  __shared__ float tile[32][65];
  const int dt = blockIdx.x, h = blockIdx.y, sel = blockIdx.z;
  const float* src = (sel==0 ? wq : (sel==1 ? wk : wv)) + (size_t)h*65536;
  const int t = threadIdx.x, d0 = dt*32;
  {
    const int r = t >> 3, cc = (t & 7)*8;
    const float* p = src + (size_t)(d0+r)*64 + cc;
    const float4 v0 = *(const float4*)p;
    const float4 v1 = *(const float4*)(p+4);
    tile[r][cc+0]=v0.x; tile[r][cc+1]=v0.y; tile[r][cc+2]=v0.z; tile[r][cc+3]=v0.w;
    tile[r][cc+4]=v1.x; tile[r][cc+5]=v1.y; tile[r][cc+6]=v1.z; tile[r][cc+7]=v1.w;
  }
  __syncthreads();
  const int f = t >> 2, rr = (t & 3)*8;
  ushort8 u;
  #pragma unroll
  for (int j=0;j<8;j++) u[j] = f2bs(tile[rr+j][f]);
  const size_t n = (size_t)sel*1024 + h*64 + f;
  *(ushort8*)(Wt + n*1024 + d0 + rr) = u;
  if (dt==0 && t<64){
    const float* bs = (sel==0 ? bq : (sel==1 ? bk : bv)) + h*64;
    Bc[sel*1024 + h*64 + t] = bs[t];
  }
}

// ---------------- m97-style bf16 GEMM: C[M,N] = A[M,K] * Bt[N,K]^T + bias ----------------
// MODE 1: fp32 out0.  MODE 2: exact-gelu -> bf16 out0.  MODE 3: fused QKV epilogue.
template<int MODE>
__global__ __launch_bounds__(256) void gemm_bt(const unsigned short* __restrict__ A,
                                               const unsigned short* __restrict__ Bt,
                                               const float* __restrict__ bias,
                                               void* __restrict__ out0,
                                               void* __restrict__ out1,
                                               void* __restrict__ out2,
                                               int M, int N, int K){
  __shared__ __align__(16) unsigned short As[128*32];
  __shared__ __align__(16) unsigned short Bs[128*32];
  const int tid = threadIdx.x;
  const int wave = tid >> 6, lane = tid & 63;
  const int quad = lane >> 4, l15 = lane & 15;
  const int m0 = blockIdx.y << 7, n0 = blockIdx.x << 7;
  const int wr = (wave >> 1) << 6, wc = (wave & 1) << 6;

  floatx4 acc[4][4];
  #pragma unroll
  for (int i=0;i<4;i++)
    #pragma unroll
    for (int j=0;j<4;j++) acc[i][j] = (floatx4)0.0f;

  const int slot0 = wave*128 + lane;
  const int r0s = slot0 >> 2, c0s = (slot0 & 3)*8;
  const int slot1 = slot0 + 64;
  const int r1s = slot1 >> 2, c1s = (slot1 & 3)*8;
  const unsigned short* pa0 = A  + (size_t)(m0 + r0s)*K + c0s;
  const unsigned short* pa1 = A  + (size_t)(m0 + r1s)*K + c1s;
  const unsigned short* pb0 = Bt + (size_t)(n0 + r0s)*K + c0s;
  const unsigned short* pb1 = Bt + (size_t)(n0 + r1s)*K + c1s;

  for (int k0 = 0; k0 < K; k0 += 32){
    gl_lds16(pa0 + k0, As + wave*1024);
    gl_lds16(pa1 + k0, As + wave*1024 + 512);
    gl_lds16(pb0 + k0, Bs + wave*1024);
    gl_lds16(pb1 + k0, Bs + wave*1024 + 512);
    __syncthreads();
    bf16x8 af[4], bfv[4];
    #pragma unroll
    for (int t=0;t<4;t++){
      af[t]  = *(const bf16x8*)(As + (wr + t*16 + l15)*32 + quad*8);
      bfv[t] = *(const bf16x8*)(Bs + (wc + t*16 + l15)*32 + quad*8);
    }
    #pragma unroll
    for (int i=0;i<4;i++)
      #pragma unroll
      for (int j=0;j<4;j++)
        acc[i][j] = __builtin_amdgcn_mfma_f32_16x16x32_bf16(af[i], bfv[j], acc[i][j], 0,0,0);
    __syncthreads();
  }

  #pragma unroll
  for (int i=0;i<4;i++){
    #pragma unroll
    for (int j=0;j<4;j++){
      const int col = n0 + wc + j*16 + l15;
      const float bsv = bias[col];
      #pragma unroll
      for (int r=0;r<4;r++){
        const int row = m0 + wr + i*16 + quad*4 + r;
        const float v = acc[i][j][r] + bsv;
        if (MODE == 1){
          ((float*)out0)[(size_t)row*N + col] = v;
        } else if (MODE == 2){
          const float gl = 0.5f*v*(1.0f + erff(v*0.70710678118654752f));
          ((unsigned short*)out0)[(size_t)row*N + col] = f2bs(gl);
        } else { // MODE 3: QKV
          if (col < 1024){
            ((unsigned short*)out0)[(size_t)row*1024 + col] = f2bs(v*0.125f);
          } else if (col < 2048){
            ((unsigned short*)out1)[(size_t)row*1024 + (col-1024)] = f2bs(v);
          } else {
            const int n = col - 2048, h = n >> 6, fidx = n & 63;
            const int b = row >> 11, s = row & 2047;
            ((unsigned short*)out2)[(size_t)(((b<<4) + h)*64 + fidx)*2048 + s] = f2bs(v);
          }
        }
      }
    }
  }
}

// ---------------- causal flash attention ----------------
// Q [8192][1024] bf16 (pre-scaled by 1/8), K [8192][1024] bf16, Vt [64][64][2048] bf16
// O [8192][1024] bf16.  Block = (qt, bh): 64 q-rows, 4 waves x 16 rows.
__global__ __launch_bounds__(256) void attn(const unsigned short* __restrict__ Q,
                                            const unsigned short* __restrict__ Kg,
                                            const unsigned short* __restrict__ Vt,
                                            unsigned short* __restrict__ O){
  __shared__ __align__(16) unsigned short Ks[64*64];
  __shared__ __align__(16) unsigned short Vs[64*64];
  __shared__ __align__(16) unsigned short Ps[4][16*72];

  const int qt = blockIdx.x, bh = blockIdx.y;
  const int b = bh >> 4, h = bh & 15;
  const int tid = threadIdx.x, wave = tid >> 6, lane = tid & 63;
  const int quad = lane >> 4, l15 = lane & 15;

  const size_t qoff = (size_t)((b<<11) + (qt<<6) + (wave<<4) + l15)*1024 + (h<<6);
  bf16x8 qf[2];
  qf[0] = *(const bf16x8*)(Q + qoff + quad*8);
  qf[1] = *(const bf16x8*)(Q + qoff + 32 + quad*8);

  floatx4 oa[4];
  #pragma unroll
  for (int i=0;i<4;i++) oa[i] = (floatx4)0.0f;
  float mi[4] = {-1e30f,-1e30f,-1e30f,-1e30f};
  float li[4] = {0.0f,0.0f,0.0f,0.0f};

  const unsigned short* Kbh = Kg + ((size_t)(b<<11))*1024 + (h<<6);
  const unsigned short* Vbh = Vt + (size_t)bh*64*2048;

  const int slot0 = wave*128 + lane;
  const int krow0 = slot0 >> 3, kc0 = (slot0 & 7) ^ (krow0 & 7);
  const int slot1 = slot0 + 64;
  const int krow1 = slot1 >> 3, kc1 = (slot1 & 7) ^ (krow1 & 7);

  for (int kt = 0; kt <= qt; ++kt){
    gl_lds16(Kbh + (size_t)((kt<<6) + krow0)*1024 + kc0*8, Ks + wave*1024);
    gl_lds16(Kbh + (size_t)((kt<<6) + krow1)*1024 + kc1*8, Ks + wave*1024 + 512);
    gl_lds16(Vbh + (size_t)krow0*2048 + (kt<<6) + kc0*8, Vs + wave*1024);
    gl_lds16(Vbh + (size_t)krow1*2048 + (kt<<6) + kc1*8, Vs + wave*1024 + 512);
    __syncthreads();

    // S = Q' K^T  (per wave: 16 q-rows x 64 kv)
    floatx4 sa[4];
    #pragma unroll
    for (int tj=0;tj<4;tj++){
      sa[tj] = (floatx4)0.0f;
      #pragma unroll
      for (int ks=0;ks<2;ks++){
        const int n = tj*16 + l15;
        const int c = (ks*4 + quad) ^ (n & 7);
        const bf16x8 kf = *(const bf16x8*)(Ks + n*64 + c*8);
        sa[tj] = __builtin_amdgcn_mfma_f32_16x16x32_bf16(qf[ks], kf, sa[tj], 0,0,0);
      }
    }

    if (kt == qt){
      #pragma unroll
      for (int tj=0;tj<4;tj++){
        const int colL = tj*16 + l15;
        #pragma unroll
        for (int r=0;r<4;r++){
          const int rowL = (wave<<4) + quad*4 + r;
          if (colL > rowL) sa[tj][r] = -1e30f;
        }
      }
    }

    // online softmax (row stats live per reg; reduce over 16-lane quad)
    #pragma unroll
    for (int r=0;r<4;r++){
      float mx = fmaxf(fmaxf(sa[0][r], sa[1][r]), fmaxf(sa[2][r], sa[3][r]));
      #pragma unroll
      for (int d=1; d<16; d<<=1) mx = fmaxf(mx, __shfl_xor(mx, d, 64));
      const float mn = fmaxf(mi[r], mx);
      const float al = __expf(mi[r] - mn);
      float rsum = 0.0f;
      #pragma unroll
      for (int tj=0;tj<4;tj++){
        const float p = __expf(sa[tj][r] - mn);
        sa[tj][r] = p;
        rsum += p;
      }
      #pragma unroll
      for (int d=1; d<16; d<<=1) rsum += __shfl_xor(rsum, d, 64);
      li[r] = li[r]*al + rsum;
      mi[r] = mn;
      #pragma unroll
      for (int tn=0;tn<4;tn++) oa[tn][r] *= al;
    }

    // P (C-layout) -> per-wave LDS -> A-layout fragments
    #pragma unroll
    for (int tj=0;tj<4;tj++)
      #pragma unroll
      for (int r=0;r<4;r++)
        Ps[wave][(quad*4+r)*72 + tj*16 + l15] = f2bs(sa[tj][r]);

    #pragma unroll
    for (int ks2=0;ks2<2;ks2++){
      const bf16x8 pf = *(const bf16x8*)(&Ps[wave][l15*72 + ks2*32 + quad*8]);
      #pragma unroll
      for (int tn=0;tn<4;tn++){
        const int n = tn*16 + l15;
        const int c = (ks2*4 + quad) ^ (n & 7);
        const bf16x8 vf = *(const bf16x8*)(Vs + n*64 + c*8);
        oa[tn] = __builtin_amdgcn_mfma_f32_16x16x32_bf16(pf, vf, oa[tn], 0,0,0);
      }
    }
    __syncthreads();
  }

  #pragma unroll
  for (int tn=0;tn<4;tn++){
    #pragma unroll
    for (int r=0;r<4;r++){
      const int qrow = (qt<<6) + (wave<<4) + quad*4 + r;
      const float v = oa[tn][r] / li[r];
      O[(size_t)((b<<11) + qrow)*1024 + (h<<6) + tn*16 + l15] = f2bs(v);
    }
  }
}

// ---------------- residual + LayerNorm (one row per block) ----------------
__global__ __launch_bounds__(256) void ln_res(const float* __restrict__ a,
                                              const float* __restrict__ bsrc,
                                              const float* __restrict__ g,
                                              const float* __restrict__ be,
                                              float* __restrict__ of,
                                              unsigned short* __restrict__ ob){
  __shared__ float red1[4], red2[4];
  const int row = blockIdx.x, t = threadIdx.x;
  const int wave = t >> 6, lane = t & 63;
  const float4 va = *(const float4*)(a + (size_t)row*1024 + t*4);
  const float4 vb = *(const float4*)(bsrc + (size_t)row*1024 + t*4);
  float xs[4] = {va.x+vb.x, va.y+vb.y, va.z+vb.z, va.w+vb.w};
  float s = xs[0]+xs[1]+xs[2]+xs[3];
  #pragma unroll
  for (int d=1; d<64; d<<=1) s += __shfl_xor(s, d, 64);
  if (lane==0) red1[wave] = s;
  __syncthreads();
  const float mean = (red1[0]+red1[1]+red1[2]+red1[3]) * (1.0f/1024.0f);
  float vsum = 0.0f;
  #pragma unroll
  for (int i=0;i<4;i++){ const float d = xs[i]-mean; vsum += d*d; }
  #pragma unroll
  for (int d=1; d<64; d<<=1) vsum += __shfl_xor(vsum, d, 64);
  if (lane==0) red2[wave] = vsum;
  __syncthreads();
  const float var = (red2[0]+red2[1]+red2[2]+red2[3]) * (1.0f/1024.0f);
  const float rs = rsqrtf(var + 1e-5f);
  const float4 gg = *(const float4*)(g + t*4);
  const float4 bb = *(const float4*)(be + t*4);
  float y[4];
  y[0] = (xs[0]-mean)*rs*gg.x + bb.x;
  y[1] = (xs[1]-mean)*rs*gg.y + bb.y;
  y[2] = (xs[2]-mean)*rs*gg.z + bb.z;
  y[3] = (xs[3]-mean)*rs*gg.w + bb.w;
  if (of){
    float4 o4; o4.x=y[0]; o4.y=y[1]; o4.z=y[2]; o4.w=y[3];
    *(float4*)(of + (size_t)row*1024 + t*4) = o4;
  }
  if (ob){
    ushort4v u = { f2bs(y[0]), f2bs(y[1]), f2bs(y[2]), f2bs(y[3]) };
    *(ushort4v*)(ob + (size_t)row*1024 + t*4) = u;
  }
}

extern "C" void kernel_launch(void* const* d_in, const int* in_sizes, int n_in,
                              void* d_out, int out_size, void* d_ws, size_t ws_size,
                              hipStream_t stream){
  (void)in_sizes; (void)n_in; (void)out_size; (void)ws_size;
  const float* x  = (const float*)d_in[0];
  const float* wq = (const float*)d_in[1];
  const float* bq = (const float*)d_in[2];
  const float* wk = (const float*)d_in[3];
  const float* bk = (const float*)d_in[4];
  const float* wv = (const float*)d_in[5];
  const float* bv = (const float*)d_in[6];
  const float* wo = (const float*)d_in[7];
  const float* bo = (const float*)d_in[8];
  const float* w1 = (const float*)d_in[9];
  const float* b1 = (const float*)d_in[10];
  const float* w2 = (const float*)d_in[11];
  const float* b2 = (const float*)d_in[12];
  const float* g1 = (const float*)d_in[13];
  const float* be1= (const float*)d_in[14];
  const float* g2 = (const float*)d_in[15];
  const float* be2= (const float*)d_in[16];
  float* out = (float*)d_out;

  char* ws = (char*)d_ws;
  size_t off = 0;
  auto take = [&](size_t bytes)->char*{
    char* p = ws + off; off += (bytes + 255) & ~(size_t)255; return p;
  };
  unsigned short* Xb  = (unsigned short*)take(8192UL*1024*2);
  unsigned short* Qb  = (unsigned short*)take(8192UL*1024*2);
  unsigned short* Kb  = (unsigned short*)take(8192UL*1024*2);
  unsigned short* Vtb = (unsigned short*)take(8192UL*1024*2);
  unsigned short* Ob  = (unsigned short*)take(8192UL*1024*2);
  unsigned short* Midb= Qb;                    // alias: spans Qb..Ob (64 MB), dead by FFN1
  unsigned short* Wqkv= (unsigned short*)take(3072UL*1024*2);
  float*          Bqkv= (float*)take(3072UL*4);
  unsigned short* Wot = (unsigned short*)take(1024UL*1024*2);
  unsigned short* W1t = (unsigned short*)take(4096UL*1024*2);
  unsigned short* W2t = (unsigned short*)take(1024UL*4096*2);
  float*          C1  = (float*)take(8192UL*1024*4);
  float*          Ff  = C1;                    // alias: attn-proj dead after LN1
  float*          Hf  = (float*)take(8192UL*1024*4);
  unsigned short* Hb  = (unsigned short*)take(8192UL*1024*2);

  // 1. pack inputs/weights to bf16 MFMA layouts
  cvt_x<<<8192, 256, 0, stream>>>(x, Xb);
  pack_qkv<<<dim3(32,16,3), 256, 0, stream>>>(wq, wk, wv, bq, bk, bv, Wqkv, Bqkv);
  transpose_pack<<<dim3(16,32),  256, 0, stream>>>(wo, Wot, 1024, 1024);
  transpose_pack<<<dim3(64,32),  256, 0, stream>>>(w1, W1t, 1024, 4096);
  transpose_pack<<<dim3(16,128), 256, 0, stream>>>(w2, W2t, 4096, 1024);

  // 2. fused QKV projection (Q pre-scaled 1/8, V stored transposed)
  gemm_bt<3><<<dim3(24,64), 256, 0, stream>>>(Xb, Wqkv, Bqkv, Qb, Kb, Vtb, 8192, 3072, 1024);

  // 3. causal flash attention
  attn<<<dim3(32,64), 256, 0, stream>>>(Qb, Kb, Vtb, Ob);

  // 4. output projection (fp32) then residual + LN1 -> h (fp32 + bf16)
  gemm_bt<1><<<dim3(8,64), 256, 0, stream>>>(Ob, Wot, bo, C1, nullptr, nullptr, 8192, 1024, 1024);
  ln_res<<<8192, 256, 0, stream>>>(x, C1, g1, be1, Hf, Hb);

  // 5. FFN: gelu(h@w1+b1)@w2+b2, then residual + LN2 -> out
  gemm_bt<2><<<dim3(32,64), 256, 0, stream>>>(Hb, W1t, b1, Midb, nullptr, nullptr, 8192, 4096, 1024);
  gemm_bt<1><<<dim3(8,64), 256, 0, stream>>>(Midb, W2t, b2, Ff, nullptr, nullptr, 8192, 1024, 4096);
  ln_res<<<8192, 256, 0, stream>>>(Hf, Ff, g2, be2, out, nullptr);
}